// Round 2
// baseline (4201.016 us; speedup 1.0000x reference)
//
#include <hip/hip_runtime.h>
#include <hip/hip_bf16.h>

#define B_ 16
#define T_ 12
#define N_ 2000
#define E_ 8000
#define M_ 32000                 // B_*N_
#define ETOT (B_*E_ + M_)        // 160000 edges incl. self loops
#define D_ 64

typedef __hip_bfloat16 bf16;

__device__ __forceinline__ float bfu(unsigned short u){ return __uint_as_float(((unsigned int)u)<<16); }
// round-to-nearest-even f32 -> bf16 bits
__device__ __forceinline__ unsigned short f2bu(float f){
  unsigned int x = __float_as_uint(f);
  x += 0x7FFFu + ((x >> 16) & 1u);
  return (unsigned short)(x >> 16);
}
__device__ __forceinline__ float wred64(float x){
  x += __shfl_xor(x,1); x += __shfl_xor(x,2); x += __shfl_xor(x,4);
  x += __shfl_xor(x,8); x += __shfl_xor(x,16); x += __shfl_xor(x,32);
  return x;
}

// ---------------- CSR build ----------------
__global__ void k_zero(int* __restrict__ p, int n){
  int i = blockIdx.x*256 + threadIdx.x; if(i<n) p[i]=0;
}

__global__ void k_hist(const int* __restrict__ ei, int* __restrict__ deg){
  int e = blockIdx.x*256 + threadIdx.x; if(e>=ETOT) return;
  int dst;
  if (e < B_*E_){ int b = e / E_; int k = e - b*E_; dst = ei[E_ + k] + b*N_; }
  else dst = e - B_*E_;
  atomicAdd(&deg[dst], 1);
}

__global__ void k_scan1(const int* __restrict__ deg, int* __restrict__ offs, int* __restrict__ bsums){
  __shared__ int s[256];
  int tid = threadIdx.x; int g = blockIdx.x*256 + tid;
  s[tid] = deg[g]; __syncthreads();
  for(int off=1; off<256; off<<=1){
    int a = (tid>=off) ? s[tid-off] : 0; __syncthreads();
    s[tid] += a; __syncthreads();
  }
  offs[g+1] = s[tid];
  if(tid==255) bsums[blockIdx.x] = s[255];
}

__global__ void k_scan2(const int* __restrict__ bsums, int* __restrict__ boffs){
  __shared__ int s[128];
  int tid = threadIdx.x;
  int v = (tid<125) ? bsums[tid] : 0;
  s[tid] = v; __syncthreads();
  for(int off=1; off<128; off<<=1){
    int a = (tid>=off) ? s[tid-off] : 0; __syncthreads();
    s[tid] += a; __syncthreads();
  }
  if(tid<125) boffs[tid] = s[tid] - v;   // exclusive block offset
}

__global__ void k_scan3(int* __restrict__ offs, const int* __restrict__ boffs){
  int tid = threadIdx.x; int g = blockIdx.x*256 + tid;
  offs[g+1] += boffs[blockIdx.x];
  if(g==0) offs[0]=0;
}

__global__ void k_scatter(const int* __restrict__ ei, const int* __restrict__ offs,
                          int* __restrict__ cursor, int* __restrict__ csr){
  int e = blockIdx.x*256 + threadIdx.x; if(e>=ETOT) return;
  int src, dst;
  if (e < B_*E_){ int b=e/E_; int k=e-b*E_; src=ei[k]+b*N_; dst=ei[E_+k]+b*N_; }
  else { src = e - B_*E_; dst = src; }
  int pos = atomicAdd(&cursor[dst], 1);
  csr[offs[dst]+pos] = src;
}

// ---------------- GAT layer 1 (in_dim=1 -> factorized) ----------------
__global__ __launch_bounds__(256) void k_gat1(
  const float* __restrict__ x_seq, const float* __restrict__ W1,
  const float* __restrict__ as1, const float* __restrict__ ad1, const float* __restrict__ b1,
  const int* __restrict__ offs, const int* __restrict__ csr,
  float* __restrict__ out1, int t)
{
  int id = blockIdx.x*256 + threadIdx.x; if(id >= M_*4) return;
  int m = id>>2, h = id&3;
  float sS=0.f, sD=0.f;
  #pragma unroll
  for(int c=0;c<8;c++){ float w=W1[h*8+c]; sS+=w*as1[h*8+c]; sD+=w*ad1[h*8+c]; }
  unsigned um=(unsigned)m, b=um/N_, n=um-b*N_;
  float xm = x_seq[(b*T_+t)*N_+n];
  float am = xm*sD;
  int e0=offs[m], e1=offs[m+1];
  float mx=-1e30f;
  for(int e=e0;e<e1;e++){
    unsigned s=(unsigned)csr[e], sb=s/N_, sn=s-sb*N_;
    float xs = x_seq[(sb*T_+t)*N_+sn];
    float ee = xs*sS + am; ee = ee>0.f ? ee : 0.2f*ee;
    mx = fmaxf(mx, ee);
  }
  float sum=0.f, ax=0.f;
  for(int e=e0;e<e1;e++){
    unsigned s=(unsigned)csr[e], sb=s/N_, sn=s-sb*N_;
    float xs = x_seq[(sb*T_+t)*N_+sn];
    float ee = xs*sS + am; ee = ee>0.f ? ee : 0.2f*ee;
    float w = expf(ee-mx); sum += w; ax += w*xs;
  }
  float A = ax / (sum + 1e-16f);
  #pragma unroll
  for(int c=0;c<8;c++){
    float v = A*W1[h*8+c] + b1[h*8+c];
    out1[(size_t)m*32 + h*8 + c] = v>0.f ? v : 0.f;
  }
}

// ---------------- GAT layer 2: features + attn scores ----------------
__global__ __launch_bounds__(256) void k_gat2a(
  const float* __restrict__ out1, const float* __restrict__ W2,
  const float* __restrict__ as2, const float* __restrict__ ad2,
  float* __restrict__ h2, float* __restrict__ asc, float* __restrict__ adc)
{
  __shared__ float W2s[2048];       // [k=32][c=64], fp32 (8KB)
  __shared__ float a2s[64], a2d[64];
  int tid = threadIdx.x;
  for(int i=tid;i<2048;i+=256) W2s[i]=W2[i];
  if(tid<64){ a2s[tid]=as2[tid]; a2d[tid]=ad2[tid]; }
  __syncthreads();
  int m = blockIdx.x*256 + tid;   // grid is exactly M_/256 blocks, no stragglers
  float x[32];
  const float4* o4 = (const float4*)(out1 + (size_t)m*32);
  #pragma unroll
  for(int k=0;k<8;k++){ float4 a=o4[k]; x[4*k]=a.x; x[4*k+1]=a.y; x[4*k+2]=a.z; x[4*k+3]=a.w; }
  #pragma unroll
  for(int cc=0;cc<4;cc++){
    float acc[16];
    #pragma unroll
    for(int c=0;c<16;c++) acc[c]=0.f;
    #pragma unroll
    for(int k=0;k<32;k++){
      float xv=x[k];
      #pragma unroll
      for(int c=0;c<16;c++) acc[c] += xv*W2s[k*64 + cc*16 + c];
    }
    float ss=0.f, sd=0.f;
    #pragma unroll
    for(int c=0;c<16;c++){
      h2[(size_t)m*64 + cc*16 + c] = acc[c];
      ss += acc[c]*a2s[cc*16+c]; sd += acc[c]*a2d[cc*16+c];
    }
    asc[m*4+cc]=ss; adc[m*4+cc]=sd;
  }
}

// ---------------- GAT layer 2: softmax-aggregate + bias + relu + PE ----------------
__global__ __launch_bounds__(256) void k_gat2b(
  const float* __restrict__ h2, const float* __restrict__ asc, const float* __restrict__ adc,
  const float* __restrict__ b2, const int* __restrict__ offs, const int* __restrict__ csr,
  float* __restrict__ seq, int t)
{
  int id = blockIdx.x*256 + threadIdx.x; if(id >= M_*4) return;
  int m = id>>2, h = id&3;
  float am = adc[m*4+h];
  int e0=offs[m], e1=offs[m+1];
  float mx=-1e30f;
  for(int e=e0;e<e1;e++){
    int s=csr[e];
    float ee = asc[s*4+h] + am; ee = ee>0.f ? ee : 0.2f*ee;
    mx = fmaxf(mx, ee);
  }
  float sum=0.f;
  float A[16];
  #pragma unroll
  for(int c=0;c<16;c++) A[c]=0.f;
  for(int e=e0;e<e1;e++){
    int s=csr[e];
    float ee = asc[s*4+h] + am; ee = ee>0.f ? ee : 0.2f*ee;
    float w = expf(ee-mx); sum += w;
    const float4* hp = (const float4*)(h2 + (size_t)s*64 + h*16);
    float4 p0=hp[0], p1=hp[1], p2=hp[2], p3=hp[3];
    A[0]+=w*p0.x; A[1]+=w*p0.y; A[2]+=w*p0.z; A[3]+=w*p0.w;
    A[4]+=w*p1.x; A[5]+=w*p1.y; A[6]+=w*p1.z; A[7]+=w*p1.w;
    A[8]+=w*p2.x; A[9]+=w*p2.y; A[10]+=w*p2.z; A[11]+=w*p2.w;
    A[12]+=w*p3.x; A[13]+=w*p3.y; A[14]+=w*p3.z; A[15]+=w*p3.w;
  }
  float inv = 1.f/(sum + 1e-16f);
  #pragma unroll
  for(int c=0;c<16;c++){
    int ch = h*16 + c;
    float v = A[c]*inv + b2[ch]; v = v>0.f ? v : 0.f;
    float ang = (float)t * expf(-0.14391156463f * (float)(ch & ~1));  // ln(1e4)/64
    float pe = (ch&1) ? cosf(ang) : sinf(ang);
    seq[((size_t)t*M_ + m)*64 + ch] = v + pe;
  }
}

// ---------------- fused attention block (qkv + attn + Wo + residual + LN) ----------------
__global__ __launch_bounds__(256) void k_attn(
  float* __restrict__ seq,
  const float* __restrict__ Wqkv, const float* __restrict__ bqkv,
  const float* __restrict__ Wo,   const float* __restrict__ bo,
  const float* __restrict__ g1,   const float* __restrict__ be1)
{
  __shared__ unsigned short wqkvT[64*192];   // [d][r] = bf16(Wqkv[r][d])  (LDS budget)
  __shared__ unsigned short woT[64*64];      // [d][c] = bf16(Wo[c][d])
  __shared__ float bq[192], boS[64], gS[64], beS[64];
  __shared__ __align__(16) float Xs[4][12][64];
  __shared__ __align__(16) float Os[4][12][64];
  int tid = threadIdx.x;
  for(int i=tid;i<12288;i+=256){ int d=i/192, r=i-d*192; wqkvT[i]=f2bu(Wqkv[r*64+d]); }
  for(int i=tid;i<4096;i+=256){ int d=i>>6, c=i&63; woT[i]=f2bu(Wo[c*64+d]); }
  if(tid<192) bq[tid]=bqkv[tid];
  if(tid<64){ boS[tid]=bo[tid]; gS[tid]=g1[tid]; beS[tid]=be1[tid]; }
  __syncthreads();

  int w = tid>>6, j = tid&63;
  int m = blockIdx.x*4 + w;
  #pragma unroll
  for(int t=0;t<12;t++) Xs[w][t][j] = seq[((size_t)t*M_ + m)*64 + j];
  __syncthreads();

  // qkv: lane j holds column j of q,k,v across all t
  float q[12],k[12],v[12];
  #pragma unroll
  for(int t=0;t<12;t++){ q[t]=bq[j]; k[t]=bq[64+j]; v[t]=bq[128+j]; }
  const float4* X4 = (const float4*)(&Xs[w][0][0]);
  #pragma unroll
  for(int d4=0; d4<16; d4++){
    float4 xv[12];
    #pragma unroll
    for(int t=0;t<12;t++) xv[t]=X4[t*16+d4];
    #pragma unroll
    for(int u=0;u<4;u++){
      int d = d4*4+u;
      float a  = bfu(wqkvT[d*192 + j]);
      float bb = bfu(wqkvT[d*192 + 64 + j]);
      float cw = bfu(wqkvT[d*192 + 128 + j]);
      #pragma unroll
      for(int t=0;t<12;t++){
        float x = (u==0)?xv[t].x:(u==1)?xv[t].y:(u==2)?xv[t].z:xv[t].w;
        q[t]+=x*a; k[t]+=x*bb; v[t]+=x*cw;
      }
    }
  }

  // per-head attention: 16-lane shuffle reductions within head group
  float oreg[12];
  #pragma unroll
  for(int t=0;t<12;t++){
    float s[12];
    #pragma unroll
    for(int t2=0;t2<12;t2++){
      float p = q[t]*k[t2];
      p += __shfl_xor(p,1); p += __shfl_xor(p,2); p += __shfl_xor(p,4); p += __shfl_xor(p,8);
      s[t2] = p*0.25f;   // scale = 1/sqrt(16)
    }
    float mx = s[0];
    #pragma unroll
    for(int t2=1;t2<12;t2++) mx = fmaxf(mx, s[t2]);
    float sum=0.f;
    #pragma unroll
    for(int t2=0;t2<12;t2++){ s[t2]=expf(s[t2]-mx); sum+=s[t2]; }
    float inv = 1.f/sum;
    float acc=0.f;
    #pragma unroll
    for(int t2=0;t2<12;t2++) acc += s[t2]*v[t2];
    oreg[t] = acc*inv;
  }
  #pragma unroll
  for(int t=0;t<12;t++) Os[w][t][j]=oreg[t];
  __syncthreads();

  // Wo projection + residual + LayerNorm
  float acc[12];
  #pragma unroll
  for(int t=0;t<12;t++) acc[t]=boS[j];
  const float4* O4 = (const float4*)(&Os[w][0][0]);
  #pragma unroll
  for(int d4=0; d4<16; d4++){
    float4 ov[12];
    #pragma unroll
    for(int t=0;t<12;t++) ov[t]=O4[t*16+d4];
    #pragma unroll
    for(int u=0;u<4;u++){
      int d = d4*4+u;
      float wv = bfu(woT[d*64 + j]);
      #pragma unroll
      for(int t=0;t<12;t++){
        float x = (u==0)?ov[t].x:(u==1)?ov[t].y:(u==2)?ov[t].z:ov[t].w;
        acc[t] += x*wv;
      }
    }
  }
  #pragma unroll
  for(int t=0;t<12;t++){
    float x = Xs[w][t][j] + acc[t];
    float mu = wred64(x)*(1.f/64.f);
    float dd = x - mu;
    float var = wred64(dd*dd)*(1.f/64.f);
    float y = dd*rsqrtf(var+1e-5f)*gS[j] + beS[j];
    seq[((size_t)t*M_ + m)*64 + j] = y;
  }
}

// ---------------- fused FF + residual + LN ----------------
__global__ __launch_bounds__(256) void k_ff(
  float* __restrict__ seq,
  const float* __restrict__ Wf1, const float* __restrict__ bf1,
  const float* __restrict__ Wf2, const float* __restrict__ bf2,
  const float* __restrict__ g2,  const float* __restrict__ be2)
{
  __shared__ unsigned short f1[64*128];   // [d][r] = bf16(Wf1[r][d])
  __shared__ unsigned short f2[128*64];   // [r][c] = bf16(Wf2[c][r])
  __shared__ float b1s[128], b2s[64], gS[64], beS[64];
  __shared__ float xs[4][64], hs[4][128];
  int tid = threadIdx.x;
  for(int i=tid;i<8192;i+=256){ int d=i>>7, r=i&127; f1[i]=f2bu(Wf1[r*64+d]); }
  for(int i=tid;i<8192;i+=256){ int r=i>>6, c=i&63; f2[i]=f2bu(Wf2[c*128+r]); }
  if(tid<128) b1s[tid]=bf1[tid];
  if(tid<64){ b2s[tid]=bf2[tid]; gS[tid]=g2[tid]; beS[tid]=be2[tid]; }
  __syncthreads();

  int w = tid>>6, c = tid&63;
  for(int it=0; it<16; it++){
    size_t row = (size_t)blockIdx.x*64 + (size_t)w*16 + it;
    float* base = seq + row*64;
    float x = base[c];
    xs[w][c]=x;
    __syncthreads();
    float h0=b1s[c], h1=b1s[64+c];
    #pragma unroll
    for(int d=0;d<64;d++){
      float xd = xs[w][d];
      h0 += xd*bfu(f1[d*128 + c]);
      h1 += xd*bfu(f1[d*128 + 64 + c]);
    }
    h0 = fmaxf(h0,0.f); h1 = fmaxf(h1,0.f);
    hs[w][c]=h0; hs[w][64+c]=h1;
    __syncthreads();
    float y = b2s[c];
    #pragma unroll
    for(int r=0;r<128;r++) y += hs[w][r]*bfu(f2[r*64 + c]);
    float res = x + y;
    float mu = wred64(res)*(1.f/64.f);
    float dd = res - mu;
    float var = wred64(dd*dd)*(1.f/64.f);
    float out = dd*rsqrtf(var+1e-5f)*gS[c] + beS[c];
    base[c] = out;
    __syncthreads();
  }
}

// ---------------- prediction head ----------------
__global__ void k_head(const float* __restrict__ seq, const float* __restrict__ Wh,
                       const float* __restrict__ bh, float* __restrict__ out){
  int m = blockIdx.x*256 + threadIdx.x; if(m>=M_) return;
  const float* row = seq + ((size_t)11*M_ + m)*64;
  float a0=bh[0], a1=bh[1], a2=bh[2];
  #pragma unroll
  for(int d=0;d<64;d++){
    float x = row[d];
    a0 += x*Wh[d]; a1 += x*Wh[64+d]; a2 += x*Wh[128+d];
  }
  unsigned b=(unsigned)m/N_, n=(unsigned)m-b*N_;
  out[(b*3+0)*N_+n] = a0;
  out[(b*3+1)*N_+n] = a1;
  out[(b*3+2)*N_+n] = a2;
}

extern "C" void kernel_launch(void* const* d_in, const int* in_sizes, int n_in,
                              void* d_out, int out_size, void* d_ws, size_t ws_size,
                              hipStream_t stream)
{
  const float* x_seq=(const float*)d_in[0];
  const int*   ei   =(const int*)d_in[1];
  const float* W1   =(const float*)d_in[2];
  const float* as1  =(const float*)d_in[3];
  const float* ad1  =(const float*)d_in[4];
  const float* b1   =(const float*)d_in[5];
  const float* W2   =(const float*)d_in[6];
  const float* as2  =(const float*)d_in[7];
  const float* ad2  =(const float*)d_in[8];
  const float* b2   =(const float*)d_in[9];
  const float* Wqkv =(const float*)d_in[10];
  const float* bqkv =(const float*)d_in[11];
  const float* Wo   =(const float*)d_in[12];
  const float* bo   =(const float*)d_in[13];
  const float* Wf1  =(const float*)d_in[14];
  const float* bf1p =(const float*)d_in[15];
  const float* Wf2  =(const float*)d_in[16];
  const float* bf2p =(const float*)d_in[17];
  const float* g1   =(const float*)d_in[18];
  const float* be1  =(const float*)d_in[19];
  const float* g2   =(const float*)d_in[20];
  const float* be2  =(const float*)d_in[21];
  const float* Wh   =(const float*)d_in[22];
  const float* bh   =(const float*)d_in[23];

  // workspace layout (fp32 region then int region), ~113 MB total
  float* seq  = (float*)d_ws;           // [T][M][64]    24,576,000 f
  float* out1 = seq  + 24576000;        // [M][32]        1,024,000 f
  float* h2   = out1 + 1024000;         // [M][64]        2,048,000 f
  float* asc  = h2   + 2048000;         // [M][4]
  float* adc  = asc  + 128000;          // [M][4]
  int* deg    = (int*)(adc + 128000);
  int* cursor = deg + M_;
  int* offs   = cursor + M_;            // M_+1 used
  int* bsums  = offs + (M_ + 2);
  int* boffs  = bsums + 128;
  int* csr    = boffs + 128;            // ETOT

  // CSR build (once per launch; edge list identical for all t)
  k_zero   <<<dim3((2*M_+255)/256), dim3(256), 0, stream>>>(deg, 2*M_);
  k_hist   <<<dim3((ETOT+255)/256), dim3(256), 0, stream>>>(ei, deg);
  k_scan1  <<<dim3(125), dim3(256), 0, stream>>>(deg, offs, bsums);
  k_scan2  <<<dim3(1),   dim3(128), 0, stream>>>(bsums, boffs);
  k_scan3  <<<dim3(125), dim3(256), 0, stream>>>(offs, boffs);
  k_scatter<<<dim3((ETOT+255)/256), dim3(256), 0, stream>>>(ei, offs, cursor, csr);

  for(int t=0;t<T_;t++){
    k_gat1 <<<dim3(500), dim3(256), 0, stream>>>(x_seq, W1, as1, ad1, b1, offs, csr, out1, t);
    k_gat2a<<<dim3(125), dim3(256), 0, stream>>>(out1, W2, as2, ad2, h2, asc, adc);
    k_gat2b<<<dim3(500), dim3(256), 0, stream>>>(h2, asc, adc, b2, offs, csr, seq, t);
  }

  for(int i=0;i<2;i++){
    k_attn<<<dim3(8000), dim3(256), 0, stream>>>(seq,
        Wqkv + (size_t)i*12288, bqkv + (size_t)i*192,
        Wo   + (size_t)i*4096,  bo   + (size_t)i*64,
        g1   + (size_t)i*64,    be1  + (size_t)i*64);
    k_ff  <<<dim3(6000), dim3(256), 0, stream>>>(seq,
        Wf1  + (size_t)i*8192,  bf1p + (size_t)i*128,
        Wf2  + (size_t)i*8192,  bf2p + (size_t)i*128,
        g2   + (size_t)i*64,    be2  + (size_t)i*64);
  }

  k_head<<<dim3(125), dim3(256), 0, stream>>>(seq, Wh, bh, (float*)d_out);
}

// Round 3
// 3240.967 us; speedup vs baseline: 1.2962x; 1.2962x over previous
//
#include <hip/hip_runtime.h>
#include <hip/hip_bf16.h>

#define B_ 16
#define T_ 12
#define N_ 2000
#define E_ 8000
#define M_ 32000                 // B_*N_
#define ETOT (B_*E_ + M_)        // 160000 edges incl. self loops
#define D_ 64

typedef __hip_bfloat16 bf16;
typedef unsigned short u16;

__device__ __forceinline__ float bfu(u16 u){ return __uint_as_float(((unsigned int)u)<<16); }
// round-to-nearest-even f32 -> bf16 bits
__device__ __forceinline__ u16 f2bu(float f){
  unsigned int x = __float_as_uint(f);
  x += 0x7FFFu + ((x >> 16) & 1u);
  return (u16)(x >> 16);
}
__device__ __forceinline__ float wred64(float x){
  x += __shfl_xor(x,1); x += __shfl_xor(x,2); x += __shfl_xor(x,4);
  x += __shfl_xor(x,8); x += __shfl_xor(x,16); x += __shfl_xor(x,32);
  return x;
}

// ---------------- weight prep: bf16 transposed copies in workspace ----------------
// regions (u16): wq[2][64][192] (24576) | wo[2][64][64] (8192) | f1[2][64][128] (16384) | f2[2][128][64] (16384)
__global__ void k_prep(const float* __restrict__ Wqkv, const float* __restrict__ Wo,
                       const float* __restrict__ Wf1, const float* __restrict__ Wf2,
                       u16* __restrict__ wb){
  int i = blockIdx.x*256 + threadIdx.x;   // grid covers exactly 65536
  if(i < 24576){
    int l=i/12288, j=i-l*12288, d=j/192, r=j-d*192;
    wb[i] = f2bu(Wqkv[l*12288 + r*64 + d]);
  } else if(i < 32768){
    int k=i-24576, l=k/4096, j=k-l*4096, d=j>>6, c=j&63;
    wb[i] = f2bu(Wo[l*4096 + c*64 + d]);
  } else if(i < 49152){
    int k=i-32768, l=k/8192, j=k-l*8192, d=j>>7, r=j&127;
    wb[i] = f2bu(Wf1[l*8192 + r*64 + d]);
  } else {
    int k=i-49152, l=k/8192, j=k-l*8192, r=j>>6, c=j&63;
    wb[i] = f2bu(Wf2[l*8192 + c*128 + r]);
  }
}

// ---------------- CSR build ----------------
__global__ void k_zero(int* __restrict__ p, int n){
  int i = blockIdx.x*256 + threadIdx.x; if(i<n) p[i]=0;
}

__global__ void k_hist(const int* __restrict__ ei, int* __restrict__ deg){
  int e = blockIdx.x*256 + threadIdx.x; if(e>=ETOT) return;
  int dst;
  if (e < B_*E_){ int b = e / E_; int k = e - b*E_; dst = ei[E_ + k] + b*N_; }
  else dst = e - B_*E_;
  atomicAdd(&deg[dst], 1);
}

__global__ void k_scan1(const int* __restrict__ deg, int* __restrict__ offs, int* __restrict__ bsums){
  __shared__ int s[256];
  int tid = threadIdx.x; int g = blockIdx.x*256 + tid;
  s[tid] = deg[g]; __syncthreads();
  for(int off=1; off<256; off<<=1){
    int a = (tid>=off) ? s[tid-off] : 0; __syncthreads();
    s[tid] += a; __syncthreads();
  }
  offs[g+1] = s[tid];
  if(tid==255) bsums[blockIdx.x] = s[255];
}

__global__ void k_scan2(const int* __restrict__ bsums, int* __restrict__ boffs){
  __shared__ int s[128];
  int tid = threadIdx.x;
  int v = (tid<125) ? bsums[tid] : 0;
  s[tid] = v; __syncthreads();
  for(int off=1; off<128; off<<=1){
    int a = (tid>=off) ? s[tid-off] : 0; __syncthreads();
    s[tid] += a; __syncthreads();
  }
  if(tid<125) boffs[tid] = s[tid] - v;   // exclusive block offset
}

__global__ void k_scan3(int* __restrict__ offs, const int* __restrict__ boffs){
  int tid = threadIdx.x; int g = blockIdx.x*256 + tid;
  offs[g+1] += boffs[blockIdx.x];
  if(g==0) offs[0]=0;
}

__global__ void k_scatter(const int* __restrict__ ei, const int* __restrict__ offs,
                          int* __restrict__ cursor, int* __restrict__ csr){
  int e = blockIdx.x*256 + threadIdx.x; if(e>=ETOT) return;
  int src, dst;
  if (e < B_*E_){ int b=e/E_; int k=e-b*E_; src=ei[k]+b*N_; dst=ei[E_+k]+b*N_; }
  else { src = e - B_*E_; dst = src; }
  int pos = atomicAdd(&cursor[dst], 1);
  csr[offs[dst]+pos] = src;
}

// ---------------- fused GAT1 + GAT2 feature/score kernel ----------------
// thread = (node m, quarter q). Computes GAT1 aggregation A[h] for all 4 heads
// (in_dim=1 factorization), then h2 columns q*16..q*16+15 and asc/adc for head q.
__global__ __launch_bounds__(256) void k_gat12(
  const float* __restrict__ x_seq, const float* __restrict__ W1,
  const float* __restrict__ as1, const float* __restrict__ ad1, const float* __restrict__ b1,
  const float* __restrict__ W2, const float* __restrict__ as2, const float* __restrict__ ad2,
  const int* __restrict__ offs, const int* __restrict__ csr,
  float* __restrict__ h2, float* __restrict__ asc, float* __restrict__ adc, int t)
{
  __shared__ float W2s[2048];       // [k=32][c=64] fp32
  __shared__ float a2s[64], a2d[64];
  int tid = threadIdx.x;
  for(int i=tid;i<2048;i+=256) W2s[i]=W2[i];
  if(tid<64){ a2s[tid]=as2[tid]; a2d[tid]=ad2[tid]; }
  __syncthreads();

  int id = blockIdx.x*256 + tid;     // grid 500*256 = 128000 = M_*4
  int m = id>>2, q = id&3;

  float sS[4], sD[4];
  #pragma unroll
  for(int h=0;h<4;h++){
    float a=0.f, d=0.f;
    #pragma unroll
    for(int c=0;c<8;c++){ float w=W1[h*8+c]; a+=w*as1[h*8+c]; d+=w*ad1[h*8+c]; }
    sS[h]=a; sD[h]=d;
  }
  unsigned um=(unsigned)m, b=um/N_, n=um-b*N_;
  const float* xsl = x_seq + (size_t)(b*T_+t)*N_;
  float xm = xsl[n];
  int e0=offs[m], e1=offs[m+1];
  float mx[4] = {-1e30f,-1e30f,-1e30f,-1e30f};
  for(int e=e0;e<e1;e++){
    unsigned s=(unsigned)csr[e]; unsigned sn=s - (s/N_)*N_;
    float xv = xsl[sn];
    #pragma unroll
    for(int h=0;h<4;h++){
      float ee = xv*sS[h] + xm*sD[h]; ee = ee>0.f ? ee : 0.2f*ee;
      mx[h] = fmaxf(mx[h], ee);
    }
  }
  float sum[4]={0,0,0,0}, ax[4]={0,0,0,0};
  for(int e=e0;e<e1;e++){
    unsigned s=(unsigned)csr[e]; unsigned sn=s - (s/N_)*N_;
    float xv = xsl[sn];
    #pragma unroll
    for(int h=0;h<4;h++){
      float ee = xv*sS[h] + xm*sD[h]; ee = ee>0.f ? ee : 0.2f*ee;
      float w = expf(ee-mx[h]); sum[h]+=w; ax[h]+=w*xv;
    }
  }
  float A[4];
  #pragma unroll
  for(int h=0;h<4;h++) A[h] = ax[h]/(sum[h]+1e-16f);

  // h2 row segment [q*16, q*16+16)
  float acc[16];
  #pragma unroll
  for(int c=0;c<16;c++) acc[c]=0.f;
  #pragma unroll
  for(int k=0;k<32;k++){
    int h = k>>3;
    float v = A[h]*W1[k] + b1[k]; v = v>0.f ? v : 0.f;   // relu(out1)
    #pragma unroll
    for(int c=0;c<16;c++) acc[c] += v*W2s[k*64 + q*16 + c];
  }
  float ss=0.f, sd=0.f;
  float4* h4 = (float4*)(h2 + (size_t)m*64 + q*16);
  #pragma unroll
  for(int c4=0;c4<4;c4++){
    h4[c4] = make_float4(acc[4*c4],acc[4*c4+1],acc[4*c4+2],acc[4*c4+3]);
  }
  #pragma unroll
  for(int c=0;c<16;c++){ ss += acc[c]*a2s[q*16+c]; sd += acc[c]*a2d[q*16+c]; }
  asc[m*4+q]=ss; adc[m*4+q]=sd;
}

// ---------------- GAT layer 2: softmax-aggregate + bias + relu + PE ----------------
__global__ __launch_bounds__(256) void k_gat2b(
  const float* __restrict__ h2, const float* __restrict__ asc, const float* __restrict__ adc,
  const float* __restrict__ b2, const int* __restrict__ offs, const int* __restrict__ csr,
  float* __restrict__ seq, int t)
{
  int id = blockIdx.x*256 + threadIdx.x; if(id >= M_*4) return;
  int m = id>>2, h = id&3;
  float am = adc[m*4+h];
  int e0=offs[m], e1=offs[m+1];
  float mx=-1e30f;
  for(int e=e0;e<e1;e++){
    int s=csr[e];
    float ee = asc[s*4+h] + am; ee = ee>0.f ? ee : 0.2f*ee;
    mx = fmaxf(mx, ee);
  }
  float sum=0.f;
  float A[16];
  #pragma unroll
  for(int c=0;c<16;c++) A[c]=0.f;
  for(int e=e0;e<e1;e++){
    int s=csr[e];
    float ee = asc[s*4+h] + am; ee = ee>0.f ? ee : 0.2f*ee;
    float w = expf(ee-mx); sum += w;
    const float4* hp = (const float4*)(h2 + (size_t)s*64 + h*16);
    float4 p0=hp[0], p1=hp[1], p2=hp[2], p3=hp[3];
    A[0]+=w*p0.x; A[1]+=w*p0.y; A[2]+=w*p0.z; A[3]+=w*p0.w;
    A[4]+=w*p1.x; A[5]+=w*p1.y; A[6]+=w*p1.z; A[7]+=w*p1.w;
    A[8]+=w*p2.x; A[9]+=w*p2.y; A[10]+=w*p2.z; A[11]+=w*p2.w;
    A[12]+=w*p3.x; A[13]+=w*p3.y; A[14]+=w*p3.z; A[15]+=w*p3.w;
  }
  float inv = 1.f/(sum + 1e-16f);
  #pragma unroll
  for(int c=0;c<16;c++){
    int ch = h*16 + c;
    float v = A[c]*inv + b2[ch]; v = v>0.f ? v : 0.f;
    float ang = (float)t * expf(-0.14391156463f * (float)(ch & ~1));  // ln(1e4)/64
    float pe = (ch&1) ? cosf(ang) : sinf(ang);
    seq[((size_t)t*M_ + m)*64 + ch] = v + pe;
  }
}

// ---------------- fused attention block (qkv + attn + Wo + residual + LN) ----------------
// weights read from L2-hot prepped bf16 global arrays; LDS only for X/O tiles.
__global__ __launch_bounds__(256) void k_attn(
  float* __restrict__ seq,
  const u16* __restrict__ wq,   // [64][192] bf16: [d][r], r = q|k|v column
  const u16* __restrict__ wo,   // [64][64]  bf16: [d][c]
  const float* __restrict__ bqkv, const float* __restrict__ bo,
  const float* __restrict__ g1,   const float* __restrict__ be1)
{
  __shared__ __align__(16) float Xs[4][12][64];
  __shared__ __align__(16) float Os[4][12][64];
  int tid = threadIdx.x;
  int w = tid>>6, j = tid&63;
  int m = blockIdx.x*4 + w;

  float bqj = bqkv[j], bkj = bqkv[64+j], bvj = bqkv[128+j];
  float boj = bo[j], gj = g1[j], bej = be1[j];

  #pragma unroll
  for(int t=0;t<12;t++) Xs[w][t][j] = seq[((size_t)t*M_ + m)*64 + j];
  __syncthreads();

  // qkv: lane j holds column j of q,k,v across all t
  float q[12],k[12],v[12];
  #pragma unroll
  for(int t=0;t<12;t++){ q[t]=bqj; k[t]=bkj; v[t]=bvj; }
  const float4* X4 = (const float4*)(&Xs[w][0][0]);
  #pragma unroll
  for(int d4=0; d4<16; d4++){
    float4 xv[12];
    #pragma unroll
    for(int t=0;t<12;t++) xv[t]=X4[t*16+d4];
    #pragma unroll
    for(int u=0;u<4;u++){
      int d = d4*4+u;
      float a  = bfu(wq[d*192 + j]);
      float bb = bfu(wq[d*192 + 64 + j]);
      float cw = bfu(wq[d*192 + 128 + j]);
      #pragma unroll
      for(int t=0;t<12;t++){
        float x = (u==0)?xv[t].x:(u==1)?xv[t].y:(u==2)?xv[t].z:xv[t].w;
        q[t]+=x*a; k[t]+=x*bb; v[t]+=x*cw;
      }
    }
  }

  // per-head attention: 16-lane shuffle reductions within head group
  float oreg[12];
  #pragma unroll
  for(int t=0;t<12;t++){
    float s[12];
    #pragma unroll
    for(int t2=0;t2<12;t2++){
      float p = q[t]*k[t2];
      p += __shfl_xor(p,1); p += __shfl_xor(p,2); p += __shfl_xor(p,4); p += __shfl_xor(p,8);
      s[t2] = p*0.25f;   // scale = 1/sqrt(16)
    }
    float mx = s[0];
    #pragma unroll
    for(int t2=1;t2<12;t2++) mx = fmaxf(mx, s[t2]);
    float sum=0.f;
    #pragma unroll
    for(int t2=0;t2<12;t2++){ s[t2]=expf(s[t2]-mx); sum+=s[t2]; }
    float inv = 1.f/sum;
    float acc=0.f;
    #pragma unroll
    for(int t2=0;t2<12;t2++) acc += s[t2]*v[t2];
    oreg[t] = acc*inv;
  }
  #pragma unroll
  for(int t=0;t<12;t++) Os[w][t][j]=oreg[t];
  __syncthreads();

  // Wo projection + residual + LayerNorm
  float acc[12];
  #pragma unroll
  for(int t=0;t<12;t++) acc[t]=boj;
  const float4* O4 = (const float4*)(&Os[w][0][0]);
  #pragma unroll
  for(int d4=0; d4<16; d4++){
    float4 ov[12];
    #pragma unroll
    for(int t=0;t<12;t++) ov[t]=O4[t*16+d4];
    #pragma unroll
    for(int u=0;u<4;u++){
      int d = d4*4+u;
      float wv = bfu(wo[d*64 + j]);
      #pragma unroll
      for(int t=0;t<12;t++){
        float x = (u==0)?ov[t].x:(u==1)?ov[t].y:(u==2)?ov[t].z:ov[t].w;
        acc[t] += x*wv;
      }
    }
  }
  #pragma unroll
  for(int t=0;t<12;t++){
    float x = Xs[w][t][j] + acc[t];
    float mu = wred64(x)*(1.f/64.f);
    float dd = x - mu;
    float var = wred64(dd*dd)*(1.f/64.f);
    float y = dd*rsqrtf(var+1e-5f)*gj + bej;
    seq[((size_t)t*M_ + m)*64 + j] = y;
  }
}

// ---------------- fused FF + residual + LN ----------------
__global__ __launch_bounds__(256) void k_ff(
  float* __restrict__ seq,
  const u16* __restrict__ f1g, const float* __restrict__ bf1,
  const u16* __restrict__ f2g, const float* __restrict__ bf2,
  const float* __restrict__ g2,  const float* __restrict__ be2)
{
  __shared__ u16 f1[64*128];   // [d][r]
  __shared__ u16 f2[128*64];   // [r][c]
  __shared__ float xs[4][64], hs[4][128];
  int tid = threadIdx.x;
  for(int i=tid;i<8192;i+=256) f1[i]=f1g[i];
  for(int i=tid;i<8192;i+=256) f2[i]=f2g[i];
  int w = tid>>6, c = tid&63;
  float b1a = bf1[c], b1b = bf1[64+c];
  float b2c = bf2[c], gc = g2[c], bec = be2[c];
  __syncthreads();

  for(int it=0; it<16; it++){
    size_t row = (size_t)blockIdx.x*64 + (size_t)w*16 + it;
    float* base = seq + row*64;
    float x = base[c];
    xs[w][c]=x;
    __syncthreads();
    float h0=b1a, h1=b1b;
    #pragma unroll
    for(int d=0;d<64;d++){
      float xd = xs[w][d];
      h0 += xd*bfu(f1[d*128 + c]);
      h1 += xd*bfu(f1[d*128 + 64 + c]);
    }
    h0 = fmaxf(h0,0.f); h1 = fmaxf(h1,0.f);
    hs[w][c]=h0; hs[w][64+c]=h1;
    __syncthreads();
    float y = b2c;
    #pragma unroll
    for(int r=0;r<128;r++) y += hs[w][r]*bfu(f2[r*64 + c]);
    float res = x + y;
    float mu = wred64(res)*(1.f/64.f);
    float dd = res - mu;
    float var = wred64(dd*dd)*(1.f/64.f);
    float out = dd*rsqrtf(var+1e-5f)*gc + bec;
    base[c] = out;
    __syncthreads();
  }
}

// ---------------- prediction head ----------------
__global__ void k_head(const float* __restrict__ seq, const float* __restrict__ Wh,
                       const float* __restrict__ bh, float* __restrict__ out){
  int m = blockIdx.x*256 + threadIdx.x; if(m>=M_) return;
  const float* row = seq + ((size_t)11*M_ + m)*64;
  float a0=bh[0], a1=bh[1], a2=bh[2];
  #pragma unroll
  for(int d=0;d<64;d++){
    float x = row[d];
    a0 += x*Wh[d]; a1 += x*Wh[64+d]; a2 += x*Wh[128+d];
  }
  unsigned b=(unsigned)m/N_, n=(unsigned)m-b*N_;
  out[(b*3+0)*N_+n] = a0;
  out[(b*3+1)*N_+n] = a1;
  out[(b*3+2)*N_+n] = a2;
}

extern "C" void kernel_launch(void* const* d_in, const int* in_sizes, int n_in,
                              void* d_out, int out_size, void* d_ws, size_t ws_size,
                              hipStream_t stream)
{
  const float* x_seq=(const float*)d_in[0];
  const int*   ei   =(const int*)d_in[1];
  const float* W1   =(const float*)d_in[2];
  const float* as1  =(const float*)d_in[3];
  const float* ad1  =(const float*)d_in[4];
  const float* b1   =(const float*)d_in[5];
  const float* W2   =(const float*)d_in[6];
  const float* as2  =(const float*)d_in[7];
  const float* ad2  =(const float*)d_in[8];
  const float* b2   =(const float*)d_in[9];
  const float* Wqkv =(const float*)d_in[10];
  const float* bqkv =(const float*)d_in[11];
  const float* Wo   =(const float*)d_in[12];
  const float* bo   =(const float*)d_in[13];
  const float* Wf1  =(const float*)d_in[14];
  const float* bf1p =(const float*)d_in[15];
  const float* Wf2  =(const float*)d_in[16];
  const float* bf2p =(const float*)d_in[17];
  const float* g1   =(const float*)d_in[18];
  const float* be1  =(const float*)d_in[19];
  const float* g2   =(const float*)d_in[20];
  const float* be2  =(const float*)d_in[21];
  const float* Wh   =(const float*)d_in[22];
  const float* bh   =(const float*)d_in[23];

  // workspace layout (fp32, then int, then u16 weight cache) ~113 MB
  float* seq  = (float*)d_ws;           // [T][M][64]    24,576,000 f
  float* h2   = seq  + 24576000;        // [M][64]        2,048,000 f
  float* asc  = h2   + 2048000;         // [M][4]
  float* adc  = asc  + 128000;          // [M][4]
  int* deg    = (int*)(adc + 128000);
  int* cursor = deg + M_;
  int* offs   = cursor + M_;            // M_+1 used
  int* bsums  = offs + (M_ + 2);
  int* boffs  = bsums + 128;
  int* csr    = boffs + 128;            // ETOT
  u16* wb     = (u16*)(csr + ETOT);     // 65536 u16
  u16* wq_g   = wb;                     // [2][64][192]
  u16* wo_g   = wb + 24576;             // [2][64][64]
  u16* f1_g   = wb + 32768;             // [2][64][128]
  u16* f2_g   = wb + 49152;             // [2][128][64]

  k_prep   <<<dim3(256), dim3(256), 0, stream>>>(Wqkv, Wo, Wf1, Wf2, wb);

  // CSR build (once per launch; edge list identical for all t)
  k_zero   <<<dim3((2*M_+255)/256), dim3(256), 0, stream>>>(deg, 2*M_);
  k_hist   <<<dim3((ETOT+255)/256), dim3(256), 0, stream>>>(ei, deg);
  k_scan1  <<<dim3(125), dim3(256), 0, stream>>>(deg, offs, bsums);
  k_scan2  <<<dim3(1),   dim3(128), 0, stream>>>(bsums, boffs);
  k_scan3  <<<dim3(125), dim3(256), 0, stream>>>(offs, boffs);
  k_scatter<<<dim3((ETOT+255)/256), dim3(256), 0, stream>>>(ei, offs, cursor, csr);

  for(int t=0;t<T_;t++){
    k_gat12<<<dim3(500), dim3(256), 0, stream>>>(x_seq, W1, as1, ad1, b1,
                                                 W2, as2, ad2, offs, csr, h2, asc, adc, t);
    k_gat2b<<<dim3(500), dim3(256), 0, stream>>>(h2, asc, adc, b2, offs, csr, seq, t);
  }

  for(int i=0;i<2;i++){
    k_attn<<<dim3(8000), dim3(256), 0, stream>>>(seq,
        wq_g + (size_t)i*12288, wo_g + (size_t)i*4096,
        bqkv + (size_t)i*192,   bo   + (size_t)i*64,
        g1   + (size_t)i*64,    be1  + (size_t)i*64);
    k_ff  <<<dim3(6000), dim3(256), 0, stream>>>(seq,
        f1_g + (size_t)i*8192,  bf1p + (size_t)i*128,
        f2_g + (size_t)i*8192,  bf2p + (size_t)i*128,
        g2   + (size_t)i*64,    be2  + (size_t)i*64);
  }

  k_head<<<dim3(125), dim3(256), 0, stream>>>(seq, Wh, bh, (float*)d_out);
}

// Round 4
// 1712.980 us; speedup vs baseline: 2.4525x; 1.8920x over previous
//
#include <hip/hip_runtime.h>
#include <hip/hip_bf16.h>

#define B_ 16
#define T_ 12
#define N_ 2000
#define E_ 8000
#define M_ 32000                 // B_*N_
#define ETOT (B_*E_ + M_)        // 160000 edges incl. self loops
#define D_ 64
#define TB_ 4                    // timesteps batched per GAT launch

typedef __hip_bfloat16 bf16;
typedef unsigned short u16;

__device__ __forceinline__ float bfu(u16 u){ return __uint_as_float(((unsigned int)u)<<16); }
__device__ __forceinline__ u16 f2bu(float f){
  unsigned int x = __float_as_uint(f);
  x += 0x7FFFu + ((x >> 16) & 1u);
  return (u16)(x >> 16);
}
__device__ __forceinline__ float wred64(float x){
  x += __shfl_xor(x,1); x += __shfl_xor(x,2); x += __shfl_xor(x,4);
  x += __shfl_xor(x,8); x += __shfl_xor(x,16); x += __shfl_xor(x,32);
  return x;
}

// ---------------- weight prep ----------------
// wqP u16 [L][16][3][64][4]: bf16(Wqkv[l][s*64+j][d4*4+u])      24576
// woP u16 [L][16][64][4]   : bf16(Wo[l][j*64 + d4*4+u])          8192
// W2T f32 [L][128][64]     : Wf2[l][j*128 + hc]                 16384
__global__ void k_prep(const float* __restrict__ Wqkv, const float* __restrict__ Wo,
                       const float* __restrict__ Wf2,
                       u16* __restrict__ wqP, u16* __restrict__ woP, float* __restrict__ W2T){
  int i = blockIdx.x*256 + threadIdx.x;    // 192 blocks -> 49152 threads exactly
  if(i < 24576){
    int l=i/12288, r0=i-l*12288;
    int d4=r0/768, r1=r0-d4*768;
    int s=r1/256, r2=r1-s*256;
    int jj=r2>>2, u=r2&3;
    wqP[i] = f2bu(Wqkv[l*12288 + (s*64+jj)*64 + d4*4+u]);
  } else if(i < 32768){
    int k2=i-24576;
    int l=k2/4096, r0=k2-l*4096;
    int d4=r0/256, r1=r0-d4*256, jj=r1>>2, u=r1&3;
    woP[k2] = f2bu(Wo[l*4096 + jj*64 + d4*4+u]);
  } else {
    int k2=i-32768;
    int l=k2/8192, r0=k2-l*8192;
    int hc=r0>>6, jj=r0&63;
    W2T[k2] = Wf2[l*8192 + jj*128 + hc];
  }
}

// ---------------- CSR build ----------------
__global__ void k_zero(int* __restrict__ p, int n){
  int i = blockIdx.x*256 + threadIdx.x; if(i<n) p[i]=0;
}

__global__ void k_hist(const int* __restrict__ ei, int* __restrict__ deg){
  int e = blockIdx.x*256 + threadIdx.x; if(e>=ETOT) return;
  int dst;
  if (e < B_*E_){ int b = e / E_; int k = e - b*E_; dst = ei[E_ + k] + b*N_; }
  else dst = e - B_*E_;
  atomicAdd(&deg[dst], 1);
}

__global__ void k_scan1(const int* __restrict__ deg, int* __restrict__ offs, int* __restrict__ bsums){
  __shared__ int s[256];
  int tid = threadIdx.x; int g = blockIdx.x*256 + tid;
  s[tid] = deg[g]; __syncthreads();
  for(int off=1; off<256; off<<=1){
    int a = (tid>=off) ? s[tid-off] : 0; __syncthreads();
    s[tid] += a; __syncthreads();
  }
  offs[g+1] = s[tid];
  if(tid==255) bsums[blockIdx.x] = s[255];
}

__global__ void k_scan2(const int* __restrict__ bsums, int* __restrict__ boffs){
  __shared__ int s[128];
  int tid = threadIdx.x;
  int v = (tid<125) ? bsums[tid] : 0;
  s[tid] = v; __syncthreads();
  for(int off=1; off<128; off<<=1){
    int a = (tid>=off) ? s[tid-off] : 0; __syncthreads();
    s[tid] += a; __syncthreads();
  }
  if(tid<125) boffs[tid] = s[tid] - v;
}

__global__ void k_scan3(int* __restrict__ offs, const int* __restrict__ boffs){
  int tid = threadIdx.x; int g = blockIdx.x*256 + tid;
  offs[g+1] += boffs[blockIdx.x];
  if(g==0) offs[0]=0;
}

__global__ void k_scatter(const int* __restrict__ ei, const int* __restrict__ offs,
                          int* __restrict__ cursor, int* __restrict__ csr){
  int e = blockIdx.x*256 + threadIdx.x; if(e>=ETOT) return;
  int src, dst;
  if (e < B_*E_){ int b=e/E_; int k=e-b*E_; src=ei[k]+b*N_; dst=ei[E_+k]+b*N_; }
  else { src = e - B_*E_; dst = src; }
  int pos = atomicAdd(&cursor[dst], 1);
  csr[offs[dst]+pos] = src;
}

// ---------------- fused GAT1 + GAT2 feature/score, batched over TB_ timesteps ----
__global__ __launch_bounds__(256) void k_gat12(
  const float* __restrict__ x_seq, const float* __restrict__ W1,
  const float* __restrict__ as1, const float* __restrict__ ad1, const float* __restrict__ b1,
  const float* __restrict__ W2, const float* __restrict__ as2, const float* __restrict__ ad2,
  const int* __restrict__ offs, const int* __restrict__ csr,
  u16* __restrict__ h2u, float* __restrict__ asc, float* __restrict__ adc, int t0)
{
  __shared__ float W2s[2048];       // [k=32][c=64] fp32
  __shared__ float a2s[64], a2d[64];
  int tid = threadIdx.x;
  for(int i=tid;i<2048;i+=256) W2s[i]=W2[i];
  if(tid<64){ a2s[tid]=as2[tid]; a2d[tid]=ad2[tid]; }
  __syncthreads();

  int tb = blockIdx.y, t = t0 + tb;
  int id = blockIdx.x*256 + tid;     // 500*256 = M_*4
  int m = id>>2, q = id&3;

  float sS[4], sD[4];
  #pragma unroll
  for(int h=0;h<4;h++){
    float a=0.f, d=0.f;
    #pragma unroll
    for(int c=0;c<8;c++){ float w=W1[h*8+c]; a+=w*as1[h*8+c]; d+=w*ad1[h*8+c]; }
    sS[h]=a; sD[h]=d;
  }
  unsigned um=(unsigned)m, b=um/N_, n=um-b*N_;
  const float* xsl = x_seq + (size_t)(b*T_+t)*N_;
  float xm = xsl[n];
  int e0=offs[m], e1=offs[m+1];
  // single-pass softmax (scores are O(1): |e| << 88, no overflow risk)
  float sum[4]={0,0,0,0}, ax[4]={0,0,0,0};
  for(int e=e0;e<e1;e++){
    unsigned s=(unsigned)csr[e]; unsigned sn=s - (s/N_)*N_;
    float xv = xsl[sn];
    #pragma unroll
    for(int h=0;h<4;h++){
      float ee = xv*sS[h] + xm*sD[h]; ee = ee>0.f ? ee : 0.2f*ee;
      float w = expf(ee); sum[h]+=w; ax[h]+=w*xv;
    }
  }
  float A[4];
  #pragma unroll
  for(int h=0;h<4;h++) A[h] = ax[h]/(sum[h]+1e-16f);

  float acc[16];
  #pragma unroll
  for(int c=0;c<16;c++) acc[c]=0.f;
  #pragma unroll
  for(int k=0;k<32;k++){
    int h = k>>3;
    float v = A[h]*W1[k] + b1[k]; v = v>0.f ? v : 0.f;   // relu(out1)
    #pragma unroll
    for(int c=0;c<16;c++) acc[c] += v*W2s[k*64 + q*16 + c];
  }
  // pack bf16, 4x uint2 stores
  uint2* hp = (uint2*)(h2u + ((size_t)tb*M_ + m)*64 + q*16);
  #pragma unroll
  for(int c2=0;c2<4;c2++){
    uint2 p;
    p.x = (unsigned)f2bu(acc[4*c2+0]) | ((unsigned)f2bu(acc[4*c2+1])<<16);
    p.y = (unsigned)f2bu(acc[4*c2+2]) | ((unsigned)f2bu(acc[4*c2+3])<<16);
    hp[c2] = p;
  }
  float ss=0.f, sd=0.f;
  #pragma unroll
  for(int c=0;c<16;c++){ ss += acc[c]*a2s[q*16+c]; sd += acc[c]*a2d[q*16+c]; }
  asc[((size_t)tb*M_+m)*4+q]=ss; adc[((size_t)tb*M_+m)*4+q]=sd;
}

// ---------------- GAT2 softmax-aggregate + bias + relu + PE, batched ----------------
__global__ __launch_bounds__(256) void k_gat2b(
  const u16* __restrict__ h2u, const float* __restrict__ asc, const float* __restrict__ adc,
  const float* __restrict__ b2, const int* __restrict__ offs, const int* __restrict__ csr,
  float* __restrict__ seq, int t0)
{
  int tb = blockIdx.y, t = t0 + tb;
  int id = blockIdx.x*256 + threadIdx.x;
  int m = id>>2, h = id&3;
  float am = adc[((size_t)tb*M_+m)*4+h];
  int e0=offs[m], e1=offs[m+1];
  float sum=0.f;
  float A[16];
  #pragma unroll
  for(int c=0;c<16;c++) A[c]=0.f;
  for(int e=e0;e<e1;e++){
    int s=csr[e];
    float ee = asc[((size_t)tb*M_+s)*4+h] + am; ee = ee>0.f ? ee : 0.2f*ee;
    float w = expf(ee); sum += w;
    const uint2* hp = (const uint2*)(h2u + ((size_t)tb*M_ + s)*64 + h*16);
    #pragma unroll
    for(int c2=0;c2<4;c2++){
      uint2 p = hp[c2];
      A[4*c2+0] += w*bfu((u16)(p.x));
      A[4*c2+1] += w*bfu((u16)(p.x>>16));
      A[4*c2+2] += w*bfu((u16)(p.y));
      A[4*c2+3] += w*bfu((u16)(p.y>>16));
    }
  }
  float inv = 1.f/(sum + 1e-16f);
  #pragma unroll
  for(int c=0;c<16;c++){
    int ch = h*16 + c;
    float v = A[c]*inv + b2[ch]; v = v>0.f ? v : 0.f;
    float ang = (float)t * expf(-0.14391156463f * (float)(ch & ~1));  // ln(1e4)/64
    float pe = (ch&1) ? cosf(ang) : sinf(ang);
    seq[((size_t)t*M_ + m)*64 + ch] = v + pe;
  }
}

// ---------------- fused attention block: no-shuffle attention via LDS ----------------
__global__ __launch_bounds__(256) void k_attn(
  float* __restrict__ seq,
  const u16* __restrict__ wqP,   // [16][3][64][4] packed bf16
  const u16* __restrict__ woP,   // [16][64][4]    packed bf16
  const float* __restrict__ bqkv, const float* __restrict__ bo,
  const float* __restrict__ g1,   const float* __restrict__ be1)
{
  __shared__ __align__(16) float Xs[4][12][64];     // 12288 B
  __shared__ __align__(16) float QKV[4][3][12][68]; // 39168 B (pad 68 kills bank aliasing)
  int tid = threadIdx.x, w = tid>>6, j = tid&63;
  int m = blockIdx.x*4 + w;

  float xr[12];
  #pragma unroll
  for(int t=0;t<12;t++){ float x = seq[((size_t)t*M_ + m)*64 + j]; xr[t]=x; Xs[w][t][j]=x; }
  float bqj = bqkv[j], bkj = bqkv[64+j], bvj = bqkv[128+j];
  float boj = bo[j], gj = g1[j], bej = be1[j];
  __syncthreads();

  // phase 1: qkv projection. lane j owns column j of q,k,v for all t.
  float q[12],k[12],v[12];
  #pragma unroll
  for(int t=0;t<12;t++){ q[t]=bqj; k[t]=bkj; v[t]=bvj; }
  const ushort4* wq4 = (const ushort4*)wqP;
  #pragma unroll
  for(int d4=0; d4<16; d4++){
    float4 xv[12];
    #pragma unroll
    for(int t=0;t<12;t++) xv[t] = *(const float4*)&Xs[w][t][d4*4];
    ushort4 aq = wq4[(d4*3+0)*64 + j];
    ushort4 ak = wq4[(d4*3+1)*64 + j];
    ushort4 av = wq4[(d4*3+2)*64 + j];
    float q0=bfu(aq.x),q1=bfu(aq.y),q2=bfu(aq.z),q3=bfu(aq.w);
    float k0=bfu(ak.x),k1=bfu(ak.y),k2=bfu(ak.z),k3=bfu(ak.w);
    float v0=bfu(av.x),v1=bfu(av.y),v2=bfu(av.z),v3=bfu(av.w);
    #pragma unroll
    for(int t=0;t<12;t++){
      q[t]+=xv[t].x*q0; q[t]+=xv[t].y*q1; q[t]+=xv[t].z*q2; q[t]+=xv[t].w*q3;
      k[t]+=xv[t].x*k0; k[t]+=xv[t].y*k1; k[t]+=xv[t].z*k2; k[t]+=xv[t].w*k3;
      v[t]+=xv[t].x*v0; v[t]+=xv[t].y*v1; v[t]+=xv[t].z*v2; v[t]+=xv[t].w*v3;
    }
  }
  #pragma unroll
  for(int t=0;t<12;t++){ QKV[w][0][t][j]=q[t]; QKV[w][1][t][j]=k[t]; QKV[w][2][t][j]=v[t]; }
  __syncthreads();

  // phase 2: attention. 48 lanes own (head h, time t); all in-register softmax.
  if(j < 48){
    int h = j/12, t = j - h*12;
    float* qrow = &QKV[w][0][t][h*16];
    float4 a0=((float4*)qrow)[0], a1=((float4*)qrow)[1], a2=((float4*)qrow)[2], a3=((float4*)qrow)[3];
    float s[12];
    #pragma unroll
    for(int t2=0;t2<12;t2++){
      const float4* kr = (const float4*)&QKV[w][1][t2][h*16];
      float4 c0=kr[0], c1=kr[1], c2=kr[2], c3=kr[3];
      float d = a0.x*c0.x + a0.y*c0.y + a0.z*c0.z + a0.w*c0.w
              + a1.x*c1.x + a1.y*c1.y + a1.z*c1.z + a1.w*c1.w
              + a2.x*c2.x + a2.y*c2.y + a2.z*c2.z + a2.w*c2.w
              + a3.x*c3.x + a3.y*c3.y + a3.z*c3.z + a3.w*c3.w;
      s[t2] = d*0.25f;                 // 1/sqrt(16)
    }
    float mx = s[0];
    #pragma unroll
    for(int t2=1;t2<12;t2++) mx = fmaxf(mx, s[t2]);
    float sum = 0.f;
    #pragma unroll
    for(int t2=0;t2<12;t2++){ s[t2]=expf(s[t2]-mx); sum+=s[t2]; }
    float inv = 1.f/sum;
    float4 o0=make_float4(0,0,0,0), o1=o0, o2=o0, o3=o0;
    #pragma unroll
    for(int t2=0;t2<12;t2++){
      const float4* vr = (const float4*)&QKV[w][2][t2][h*16];
      float4 c0=vr[0], c1=vr[1], c2=vr[2], c3=vr[3];
      float ww = s[t2];
      o0.x+=ww*c0.x; o0.y+=ww*c0.y; o0.z+=ww*c0.z; o0.w+=ww*c0.w;
      o1.x+=ww*c1.x; o1.y+=ww*c1.y; o1.z+=ww*c1.z; o1.w+=ww*c1.w;
      o2.x+=ww*c2.x; o2.y+=ww*c2.y; o2.z+=ww*c2.z; o2.w+=ww*c2.w;
      o3.x+=ww*c3.x; o3.y+=ww*c3.y; o3.z+=ww*c3.z; o3.w+=ww*c3.w;
    }
    o0.x*=inv;o0.y*=inv;o0.z*=inv;o0.w*=inv;
    o1.x*=inv;o1.y*=inv;o1.z*=inv;o1.w*=inv;
    o2.x*=inv;o2.y*=inv;o2.z*=inv;o2.w*=inv;
    o3.x*=inv;o3.y*=inv;o3.z*=inv;o3.w*=inv;
    ((float4*)qrow)[0]=o0; ((float4*)qrow)[1]=o1; ((float4*)qrow)[2]=o2; ((float4*)qrow)[3]=o3;
  }
  __syncthreads();

  // phase 3: Wo + residual + LN (O sits in QKV[w][0])
  float acc[12];
  #pragma unroll
  for(int t=0;t<12;t++) acc[t]=boj;
  const ushort4* wo4 = (const ushort4*)woP;
  #pragma unroll
  for(int d4=0; d4<16; d4++){
    ushort4 aw = wo4[d4*64 + j];
    float w0=bfu(aw.x), w1=bfu(aw.y), w2=bfu(aw.z), w3=bfu(aw.w);
    #pragma unroll
    for(int t=0;t<12;t++){
      float4 ov = *(const float4*)&QKV[w][0][t][d4*4];
      acc[t]+=ov.x*w0; acc[t]+=ov.y*w1; acc[t]+=ov.z*w2; acc[t]+=ov.w*w3;
    }
  }
  #pragma unroll
  for(int t=0;t<12;t++){
    float x = xr[t] + acc[t];
    float mu = wred64(x)*(1.f/64.f);
    float dd = x - mu;
    float var = wred64(dd*dd)*(1.f/64.f);
    float y = dd*rsqrtf(var+1e-5f)*gj + bej;
    seq[((size_t)t*M_ + m)*64 + j] = y;
  }
}

// ---------------- FF + residual + LN: lane-per-row, scalar-pipe weights ----------------
__global__ __launch_bounds__(256,2) void k_ff(
  float* __restrict__ seq,
  const float* __restrict__ Wf1, const float* __restrict__ bf1,
  const float* __restrict__ W2T, const float* __restrict__ bf2,
  const float* __restrict__ g2,  const float* __restrict__ be2)
{
  size_t r = (size_t)blockIdx.x*256 + threadIdx.x;   // row id; grid=1500 -> 384000 rows
  float* base = seq + r*64;
  float x[64];
  #pragma unroll
  for(int i=0;i<16;i++){
    float4 a = ((const float4*)base)[i];
    x[4*i]=a.x; x[4*i+1]=a.y; x[4*i+2]=a.z; x[4*i+3]=a.w;
  }
  float y[64];
  #pragma unroll
  for(int j=0;j<64;j++) y[j]=bf2[j];

  #pragma unroll 1
  for(int hc=0;hc<128;hc++){
    const float* w1 = Wf1 + hc*64;     // wave-uniform -> s_load
    float h0=0.f,h1=0.f,h2=0.f,h3=0.f;
    #pragma unroll
    for(int d=0;d<64;d+=4){
      h0 += x[d]*w1[d]; h1 += x[d+1]*w1[d+1];
      h2 += x[d+2]*w1[d+2]; h3 += x[d+3]*w1[d+3];
    }
    float h = (h0+h1)+(h2+h3) + bf1[hc];
    h = fmaxf(h, 0.f);
    const float* w2 = W2T + hc*64;     // wave-uniform -> s_load
    #pragma unroll
    for(int j=0;j<64;j++) y[j] += h*w2[j];
  }

  // residual + LayerNorm fully in-lane
  float mu=0.f;
  #pragma unroll
  for(int j=0;j<64;j++){ y[j] += x[j]; mu += y[j]; }
  mu *= (1.f/64.f);
  float var=0.f;
  #pragma unroll
  for(int j=0;j<64;j++){ float d=y[j]-mu; var += d*d; }
  float sc = rsqrtf(var*(1.f/64.f) + 1e-5f);
  #pragma unroll
  for(int i=0;i<16;i++){
    float4 o;
    o.x=(y[4*i  ]-mu)*sc*g2[4*i  ]+be2[4*i  ];
    o.y=(y[4*i+1]-mu)*sc*g2[4*i+1]+be2[4*i+1];
    o.z=(y[4*i+2]-mu)*sc*g2[4*i+2]+be2[4*i+2];
    o.w=(y[4*i+3]-mu)*sc*g2[4*i+3]+be2[4*i+3];
    ((float4*)base)[i]=o;
  }
}

// ---------------- prediction head ----------------
__global__ void k_head(const float* __restrict__ seq, const float* __restrict__ Wh,
                       const float* __restrict__ bh, float* __restrict__ out){
  int m = blockIdx.x*256 + threadIdx.x; if(m>=M_) return;
  const float* row = seq + ((size_t)11*M_ + m)*64;
  float a0=bh[0], a1=bh[1], a2=bh[2];
  #pragma unroll
  for(int d=0;d<64;d++){
    float x = row[d];
    a0 += x*Wh[d]; a1 += x*Wh[64+d]; a2 += x*Wh[128+d];
  }
  unsigned b=(unsigned)m/N_, n=(unsigned)m-b*N_;
  out[(b*3+0)*N_+n] = a0;
  out[(b*3+1)*N_+n] = a1;
  out[(b*3+2)*N_+n] = a2;
}

extern "C" void kernel_launch(void* const* d_in, const int* in_sizes, int n_in,
                              void* d_out, int out_size, void* d_ws, size_t ws_size,
                              hipStream_t stream)
{
  const float* x_seq=(const float*)d_in[0];
  const int*   ei   =(const int*)d_in[1];
  const float* W1   =(const float*)d_in[2];
  const float* as1  =(const float*)d_in[3];
  const float* ad1  =(const float*)d_in[4];
  const float* b1   =(const float*)d_in[5];
  const float* W2   =(const float*)d_in[6];
  const float* as2  =(const float*)d_in[7];
  const float* ad2  =(const float*)d_in[8];
  const float* b2   =(const float*)d_in[9];
  const float* Wqkv =(const float*)d_in[10];
  const float* bqkv =(const float*)d_in[11];
  const float* Wo   =(const float*)d_in[12];
  const float* bo   =(const float*)d_in[13];
  const float* Wf1  =(const float*)d_in[14];
  const float* bf1p =(const float*)d_in[15];
  const float* Wf2  =(const float*)d_in[16];
  const float* bf2p =(const float*)d_in[17];
  const float* g1   =(const float*)d_in[18];
  const float* be1  =(const float*)d_in[19];
  const float* g2   =(const float*)d_in[20];
  const float* be2  =(const float*)d_in[21];
  const float* Wh   =(const float*)d_in[22];
  const float* bh   =(const float*)d_in[23];

  // workspace layout (~120 MB)
  float* seq  = (float*)d_ws;            // [T][M][64]    24,576,000 f
  float* asc  = seq  + 24576000;         // [TB_][M][4]      512,000 f
  float* adc  = asc  + 512000;           //                  512,000 f
  float* W2T  = adc  + 512000;           // [2][128][64]      16,384 f
  int* deg    = (int*)(W2T + 16384);
  int* cursor = deg + M_;
  int* offs   = cursor + M_;             // M_+1 used
  int* bsums  = offs + (M_ + 2);
  int* boffs  = bsums + 128;
  int* csr    = boffs + 128;             // ETOT
  u16* h2u    = (u16*)(csr + ETOT);      // [TB_][M][64]  8,192,000 u16
  u16* wqP    = h2u + (size_t)TB_*M_*64; // 24576
  u16* woP    = wqP + 24576;             // 8192

  k_prep   <<<dim3(192), dim3(256), 0, stream>>>(Wqkv, Wo, Wf2, wqP, woP, W2T);

  // CSR build (edge list identical for all t)
  k_zero   <<<dim3((2*M_+255)/256), dim3(256), 0, stream>>>(deg, 2*M_);
  k_hist   <<<dim3((ETOT+255)/256), dim3(256), 0, stream>>>(ei, deg);
  k_scan1  <<<dim3(125), dim3(256), 0, stream>>>(deg, offs, bsums);
  k_scan2  <<<dim3(1),   dim3(128), 0, stream>>>(bsums, boffs);
  k_scan3  <<<dim3(125), dim3(256), 0, stream>>>(offs, boffs);
  k_scatter<<<dim3((ETOT+255)/256), dim3(256), 0, stream>>>(ei, offs, cursor, csr);

  for(int t0=0; t0<T_; t0+=TB_){
    k_gat12<<<dim3(500,TB_), dim3(256), 0, stream>>>(x_seq, W1, as1, ad1, b1,
                                                     W2, as2, ad2, offs, csr, h2u, asc, adc, t0);
    k_gat2b<<<dim3(500,TB_), dim3(256), 0, stream>>>(h2u, asc, adc, b2, offs, csr, seq, t0);
  }

  for(int i=0;i<2;i++){
    k_attn<<<dim3(8000), dim3(256), 0, stream>>>(seq,
        wqP + (size_t)i*12288, woP + (size_t)i*4096,
        bqkv + (size_t)i*192,  bo   + (size_t)i*64,
        g1   + (size_t)i*64,   be1  + (size_t)i*64);
    k_ff  <<<dim3(1500), dim3(256), 0, stream>>>(seq,
        Wf1  + (size_t)i*8192, bf1p + (size_t)i*128,
        W2T  + (size_t)i*8192, bf2p + (size_t)i*64,
        g2   + (size_t)i*64,   be2  + (size_t)i*64);
  }

  k_head<<<dim3(125), dim3(256), 0, stream>>>(seq, Wh, bh, (float*)d_out);
}

// Round 5
// 1473.530 us; speedup vs baseline: 2.8510x; 1.1625x over previous
//
#include <hip/hip_runtime.h>
#include <hip/hip_bf16.h>

#define B_ 16
#define T_ 12
#define N_ 2000
#define E_ 8000
#define M_ 32000                 // B_*N_
#define ETOT (B_*E_ + M_)        // 160000 edges incl. self loops
#define D_ 64
#define TB_ 4                    // timesteps batched per GAT launch

typedef __hip_bfloat16 bf16;
typedef unsigned short u16;

__device__ __forceinline__ float bfu(u16 u){ return __uint_as_float(((unsigned int)u)<<16); }
__device__ __forceinline__ u16 f2bu(float f){
  unsigned int x = __float_as_uint(f);
  x += 0x7FFFu + ((x >> 16) & 1u);
  return (u16)(x >> 16);
}
__device__ __forceinline__ float wred64(float x){
  x += __shfl_xor(x,1); x += __shfl_xor(x,2); x += __shfl_xor(x,4);
  x += __shfl_xor(x,8); x += __shfl_xor(x,16); x += __shfl_xor(x,32);
  return x;
}

// ---------------- weight prep ----------------
// wqP u16 [L][16][3][64][4]: bf16(Wqkv[l][s*64+j][d4*4+u])      24576
// woP u16 [L][16][64][4]   : bf16(Wo[l][j*64 + d4*4+u])          8192
// W2T f32 [L][128][64]     : Wf2[l][j*128 + hc]                 16384
__global__ void k_prep(const float* __restrict__ Wqkv, const float* __restrict__ Wo,
                       const float* __restrict__ Wf2,
                       u16* __restrict__ wqP, u16* __restrict__ woP, float* __restrict__ W2T){
  int i = blockIdx.x*256 + threadIdx.x;    // 192 blocks -> 49152 threads exactly
  if(i < 24576){
    int l=i/12288, r0=i-l*12288;
    int d4=r0/768, r1=r0-d4*768;
    int s=r1/256, r2=r1-s*256;
    int jj=r2>>2, u=r2&3;
    wqP[i] = f2bu(Wqkv[l*12288 + (s*64+jj)*64 + d4*4+u]);
  } else if(i < 32768){
    int k2=i-24576;
    int l=k2/4096, r0=k2-l*4096;
    int d4=r0/256, r1=r0-d4*256, jj=r1>>2, u=r1&3;
    woP[k2] = f2bu(Wo[l*4096 + jj*64 + d4*4+u]);
  } else {
    int k2=i-32768;
    int l=k2/8192, r0=k2-l*8192;
    int hc=r0>>6, jj=r0&63;
    W2T[k2] = Wf2[l*8192 + jj*128 + hc];
  }
}

// ---------------- CSR build ----------------
__global__ void k_zero(int* __restrict__ p, int n){
  int i = blockIdx.x*256 + threadIdx.x; if(i<n) p[i]=0;
}

__global__ void k_hist(const int* __restrict__ ei, int* __restrict__ deg){
  int e = blockIdx.x*256 + threadIdx.x; if(e>=ETOT) return;
  int dst;
  if (e < B_*E_){ int b = e / E_; int k = e - b*E_; dst = ei[E_ + k] + b*N_; }
  else dst = e - B_*E_;
  atomicAdd(&deg[dst], 1);
}

__global__ void k_scan1(const int* __restrict__ deg, int* __restrict__ offs, int* __restrict__ bsums){
  __shared__ int s[256];
  int tid = threadIdx.x; int g = blockIdx.x*256 + tid;
  s[tid] = deg[g]; __syncthreads();
  for(int off=1; off<256; off<<=1){
    int a = (tid>=off) ? s[tid-off] : 0; __syncthreads();
    s[tid] += a; __syncthreads();
  }
  offs[g+1] = s[tid];
  if(tid==255) bsums[blockIdx.x] = s[255];
}

__global__ void k_scan2(const int* __restrict__ bsums, int* __restrict__ boffs){
  __shared__ int s[128];
  int tid = threadIdx.x;
  int v = (tid<125) ? bsums[tid] : 0;
  s[tid] = v; __syncthreads();
  for(int off=1; off<128; off<<=1){
    int a = (tid>=off) ? s[tid-off] : 0; __syncthreads();
    s[tid] += a; __syncthreads();
  }
  if(tid<125) boffs[tid] = s[tid] - v;
}

__global__ void k_scan3(int* __restrict__ offs, const int* __restrict__ boffs){
  int tid = threadIdx.x; int g = blockIdx.x*256 + tid;
  offs[g+1] += boffs[blockIdx.x];
  if(g==0) offs[0]=0;
}

__global__ void k_scatter(const int* __restrict__ ei, const int* __restrict__ offs,
                          int* __restrict__ cursor, int* __restrict__ csr){
  int e = blockIdx.x*256 + threadIdx.x; if(e>=ETOT) return;
  int src, dst;
  if (e < B_*E_){ int b=e/E_; int k=e-b*E_; src=ei[k]+b*N_; dst=ei[E_+k]+b*N_; }
  else { src = e - B_*E_; dst = src; }
  int pos = atomicAdd(&cursor[dst], 1);
  csr[offs[dst]+pos] = src;
}

// ---------------- fused GAT1 + GAT2 feature/score, batched over TB_ timesteps ----
__global__ __launch_bounds__(256) void k_gat12(
  const float* __restrict__ x_seq, const float* __restrict__ W1,
  const float* __restrict__ as1, const float* __restrict__ ad1, const float* __restrict__ b1,
  const float* __restrict__ W2, const float* __restrict__ as2, const float* __restrict__ ad2,
  const int* __restrict__ offs, const int* __restrict__ csr,
  u16* __restrict__ h2u, float* __restrict__ asc, float* __restrict__ adc, int t0)
{
  __shared__ float W2s[2048];       // [k=32][c=64] fp32
  __shared__ float a2s[64], a2d[64];
  int tid = threadIdx.x;
  for(int i=tid;i<2048;i+=256) W2s[i]=W2[i];
  if(tid<64){ a2s[tid]=as2[tid]; a2d[tid]=ad2[tid]; }
  __syncthreads();

  int tb = blockIdx.y, t = t0 + tb;
  int id = blockIdx.x*256 + tid;     // 500*256 = M_*4
  int m = id>>2, q = id&3;

  float sS[4], sD[4];
  #pragma unroll
  for(int h=0;h<4;h++){
    float a=0.f, d=0.f;
    #pragma unroll
    for(int c=0;c<8;c++){ float w=W1[h*8+c]; a+=w*as1[h*8+c]; d+=w*ad1[h*8+c]; }
    sS[h]=a; sD[h]=d;
  }
  unsigned um=(unsigned)m, b=um/N_, n=um-b*N_;
  const float* xsl = x_seq + (size_t)(b*T_+t)*N_;
  float xm = xsl[n];
  int e0=offs[m], e1=offs[m+1];
  // single-pass softmax (scores are O(1): no overflow risk)
  float sum[4]={0,0,0,0}, ax[4]={0,0,0,0};
  for(int e=e0;e<e1;e++){
    unsigned s=(unsigned)csr[e]; unsigned sn=s - (s/N_)*N_;
    float xv = xsl[sn];
    #pragma unroll
    for(int h=0;h<4;h++){
      float ee = xv*sS[h] + xm*sD[h]; ee = ee>0.f ? ee : 0.2f*ee;
      float w = __expf(ee); sum[h]+=w; ax[h]+=w*xv;
    }
  }
  float A[4];
  #pragma unroll
  for(int h=0;h<4;h++) A[h] = ax[h]/(sum[h]+1e-16f);

  float acc[16];
  #pragma unroll
  for(int c=0;c<16;c++) acc[c]=0.f;
  #pragma unroll
  for(int k=0;k<32;k++){
    int h = k>>3;
    float v = A[h]*W1[k] + b1[k]; v = v>0.f ? v : 0.f;   // relu(out1)
    #pragma unroll
    for(int c=0;c<16;c++) acc[c] += v*W2s[k*64 + q*16 + c];
  }
  // pack bf16, 4x uint2 stores
  uint2* hp = (uint2*)(h2u + ((size_t)tb*M_ + m)*64 + q*16);
  #pragma unroll
  for(int c2=0;c2<4;c2++){
    uint2 p;
    p.x = (unsigned)f2bu(acc[4*c2+0]) | ((unsigned)f2bu(acc[4*c2+1])<<16);
    p.y = (unsigned)f2bu(acc[4*c2+2]) | ((unsigned)f2bu(acc[4*c2+3])<<16);
    hp[c2] = p;
  }
  float ss=0.f, sd=0.f;
  #pragma unroll
  for(int c=0;c<16;c++){ ss += acc[c]*a2s[q*16+c]; sd += acc[c]*a2d[q*16+c]; }
  asc[((size_t)tb*M_+m)*4+q]=ss; adc[((size_t)tb*M_+m)*4+q]=sd;
}

// ---------------- GAT2 softmax-aggregate + bias + relu + PE, batched ----------------
__global__ __launch_bounds__(256) void k_gat2b(
  const u16* __restrict__ h2u, const float* __restrict__ asc, const float* __restrict__ adc,
  const float* __restrict__ b2, const int* __restrict__ offs, const int* __restrict__ csr,
  float* __restrict__ seq, int t0)
{
  int tb = blockIdx.y, t = t0 + tb;
  int id = blockIdx.x*256 + threadIdx.x;
  int m = id>>2, h = id&3;
  float am = adc[((size_t)tb*M_+m)*4+h];
  int e0=offs[m], e1=offs[m+1];
  float sum=0.f;
  float A[16];
  #pragma unroll
  for(int c=0;c<16;c++) A[c]=0.f;
  for(int e=e0;e<e1;e++){
    int s=csr[e];
    float ee = asc[((size_t)tb*M_+s)*4+h] + am; ee = ee>0.f ? ee : 0.2f*ee;
    float w = __expf(ee); sum += w;
    const uint2* hp = (const uint2*)(h2u + ((size_t)tb*M_ + s)*64 + h*16);
    #pragma unroll
    for(int c2=0;c2<4;c2++){
      uint2 p = hp[c2];
      A[4*c2+0] += w*bfu((u16)(p.x));
      A[4*c2+1] += w*bfu((u16)(p.x>>16));
      A[4*c2+2] += w*bfu((u16)(p.y));
      A[4*c2+3] += w*bfu((u16)(p.y>>16));
    }
  }
  float inv = 1.f/(sum + 1e-16f);
  #pragma unroll
  for(int c=0;c<16;c++){
    int ch = h*16 + c;
    float v = A[c]*inv + b2[ch]; v = v>0.f ? v : 0.f;
    float ang = (float)t * __expf(-0.14391156463f * (float)(ch & ~1));  // ln(1e4)/64
    float pe = (ch&1) ? __cosf(ang) : __sinf(ang);
    seq[((size_t)t*M_ + m)*64 + ch] = v + pe;
  }
}

// ---------------- fused attention block: Xs/QKV LDS union, 4 blocks/CU ----------------
// Per-wave union: U[w][0..767] is Xs[12][64] during phase 1; U[w][s*816+t*68+c]
// is QKV[s][t][c] afterwards. Safe: only wave w touches U[w], and the QKV stores
// depend on accumulators that depend on ALL Xs loads (cannot be reordered above them).
__global__ __launch_bounds__(256) void k_attn(
  float* __restrict__ seq,
  const u16* __restrict__ wqP,   // [16][3][64][4] packed bf16
  const u16* __restrict__ woP,   // [16][64][4]    packed bf16
  const float* __restrict__ bqkv, const float* __restrict__ bo,
  const float* __restrict__ g1,   const float* __restrict__ be1)
{
  __shared__ __align__(16) float U[4][2448];   // 39168 B total
  int tid = threadIdx.x, w = tid>>6, j = tid&63;
  int m = blockIdx.x*4 + w;
  float* Uw = U[w];

  float xr[12];
  #pragma unroll
  for(int t=0;t<12;t++){ float x = seq[((size_t)t*M_ + m)*64 + j]; xr[t]=x; Uw[t*64+j]=x; }
  float bqj = bqkv[j], bkj = bqkv[64+j], bvj = bqkv[128+j];
  float boj = bo[j], gj = g1[j], bej = be1[j];
  __syncthreads();

  // phase 1: qkv projection. lane j owns column j of q,k,v for all t.
  float q[12],k[12],v[12];
  #pragma unroll
  for(int t=0;t<12;t++){ q[t]=bqj; k[t]=bkj; v[t]=bvj; }
  const ushort4* wq4 = (const ushort4*)wqP;
  #pragma unroll
  for(int d4=0; d4<16; d4++){
    float4 xv[12];
    #pragma unroll
    for(int t=0;t<12;t++) xv[t] = *(const float4*)&Uw[t*64 + d4*4];
    ushort4 aq = wq4[(d4*3+0)*64 + j];
    ushort4 ak = wq4[(d4*3+1)*64 + j];
    ushort4 av = wq4[(d4*3+2)*64 + j];
    float q0=bfu(aq.x),q1=bfu(aq.y),q2=bfu(aq.z),q3=bfu(aq.w);
    float k0=bfu(ak.x),k1=bfu(ak.y),k2=bfu(ak.z),k3=bfu(ak.w);
    float v0=bfu(av.x),v1=bfu(av.y),v2=bfu(av.z),v3=bfu(av.w);
    #pragma unroll
    for(int t=0;t<12;t++){
      q[t]+=xv[t].x*q0; q[t]+=xv[t].y*q1; q[t]+=xv[t].z*q2; q[t]+=xv[t].w*q3;
      k[t]+=xv[t].x*k0; k[t]+=xv[t].y*k1; k[t]+=xv[t].z*k2; k[t]+=xv[t].w*k3;
      v[t]+=xv[t].x*v0; v[t]+=xv[t].y*v1; v[t]+=xv[t].z*v2; v[t]+=xv[t].w*v3;
    }
  }
  #pragma unroll
  for(int t=0;t<12;t++){
    Uw[       t*68 + j]=q[t];     // QKV[0] overlays Xs — stores depend on all loads
    Uw[ 816 + t*68 + j]=k[t];
    Uw[1632 + t*68 + j]=v[t];
  }
  __syncthreads();

  // phase 2: attention. 48 lanes own (head h, time t); in-register softmax.
  if(j < 48){
    int h = j/12, t = j - h*12;
    float* qrow = &Uw[t*68 + h*16];
    float4 a0=((float4*)qrow)[0], a1=((float4*)qrow)[1], a2=((float4*)qrow)[2], a3=((float4*)qrow)[3];
    float s[12];
    #pragma unroll
    for(int t2=0;t2<12;t2++){
      const float4* kr = (const float4*)&Uw[816 + t2*68 + h*16];
      float4 c0=kr[0], c1=kr[1], c2=kr[2], c3=kr[3];
      float d = a0.x*c0.x + a0.y*c0.y + a0.z*c0.z + a0.w*c0.w
              + a1.x*c1.x + a1.y*c1.y + a1.z*c1.z + a1.w*c1.w
              + a2.x*c2.x + a2.y*c2.y + a2.z*c2.z + a2.w*c2.w
              + a3.x*c3.x + a3.y*c3.y + a3.z*c3.z + a3.w*c3.w;
      s[t2] = d*0.25f;                 // 1/sqrt(16)
    }
    float mx = s[0];
    #pragma unroll
    for(int t2=1;t2<12;t2++) mx = fmaxf(mx, s[t2]);
    float sum = 0.f;
    #pragma unroll
    for(int t2=0;t2<12;t2++){ s[t2]=__expf(s[t2]-mx); sum+=s[t2]; }
    float inv = 1.f/sum;
    float4 o0=make_float4(0,0,0,0), o1=o0, o2=o0, o3=o0;
    #pragma unroll
    for(int t2=0;t2<12;t2++){
      const float4* vr = (const float4*)&Uw[1632 + t2*68 + h*16];
      float4 c0=vr[0], c1=vr[1], c2=vr[2], c3=vr[3];
      float ww = s[t2];
      o0.x+=ww*c0.x; o0.y+=ww*c0.y; o0.z+=ww*c0.z; o0.w+=ww*c0.w;
      o1.x+=ww*c1.x; o1.y+=ww*c1.y; o1.z+=ww*c1.z; o1.w+=ww*c1.w;
      o2.x+=ww*c2.x; o2.y+=ww*c2.y; o2.z+=ww*c2.z; o2.w+=ww*c2.w;
      o3.x+=ww*c3.x; o3.y+=ww*c3.y; o3.z+=ww*c3.z; o3.w+=ww*c3.w;
    }
    o0.x*=inv;o0.y*=inv;o0.z*=inv;o0.w*=inv;
    o1.x*=inv;o1.y*=inv;o1.z*=inv;o1.w*=inv;
    o2.x*=inv;o2.y*=inv;o2.z*=inv;o2.w*=inv;
    o3.x*=inv;o3.y*=inv;o3.z*=inv;o3.w*=inv;
    ((float4*)qrow)[0]=o0; ((float4*)qrow)[1]=o1; ((float4*)qrow)[2]=o2; ((float4*)qrow)[3]=o3;
  }
  __syncthreads();

  // phase 3: Wo + residual + LN (O sits in QKV[0] region)
  float acc[12];
  #pragma unroll
  for(int t=0;t<12;t++) acc[t]=boj;
  const ushort4* wo4 = (const ushort4*)woP;
  #pragma unroll
  for(int d4=0; d4<16; d4++){
    ushort4 aw = wo4[d4*64 + j];
    float w0=bfu(aw.x), w1=bfu(aw.y), w2=bfu(aw.z), w3=bfu(aw.w);
    #pragma unroll
    for(int t=0;t<12;t++){
      float4 ov = *(const float4*)&Uw[t*68 + d4*4];
      acc[t]+=ov.x*w0; acc[t]+=ov.y*w1; acc[t]+=ov.z*w2; acc[t]+=ov.w*w3;
    }
  }
  #pragma unroll
  for(int t=0;t<12;t++){
    float x = xr[t] + acc[t];
    float mu = wred64(x)*(1.f/64.f);
    float dd = x - mu;
    float var = wred64(dd*dd)*(1.f/64.f);
    float y = dd*rsqrtf(var+1e-5f)*gj + bej;
    seq[((size_t)t*M_ + m)*64 + j] = y;
  }
}

// ---------------- FF + residual + LN: lane-per-row, scalar-pipe weights ----------------
__global__ __launch_bounds__(256,2) void k_ff(
  float* __restrict__ seq,
  const float* __restrict__ Wf1, const float* __restrict__ bf1,
  const float* __restrict__ W2T, const float* __restrict__ bf2,
  const float* __restrict__ g2,  const float* __restrict__ be2)
{
  size_t r = (size_t)blockIdx.x*256 + threadIdx.x;   // row id; grid=1500 -> 384000 rows
  float* base = seq + r*64;
  float x[64];
  #pragma unroll
  for(int i=0;i<16;i++){
    float4 a = ((const float4*)base)[i];
    x[4*i]=a.x; x[4*i+1]=a.y; x[4*i+2]=a.z; x[4*i+3]=a.w;
  }
  float y[64];
  #pragma unroll
  for(int j=0;j<64;j++) y[j]=bf2[j];

  #pragma unroll 1
  for(int hc=0;hc<128;hc++){
    const float* w1 = Wf1 + hc*64;     // wave-uniform -> s_load
    float h0=0.f,h1=0.f,h2=0.f,h3=0.f;
    #pragma unroll
    for(int d=0;d<64;d+=4){
      h0 += x[d]*w1[d]; h1 += x[d+1]*w1[d+1];
      h2 += x[d+2]*w1[d+2]; h3 += x[d+3]*w1[d+3];
    }
    float h = (h0+h1)+(h2+h3) + bf1[hc];
    h = fmaxf(h, 0.f);
    const float* w2 = W2T + hc*64;     // wave-uniform -> s_load
    #pragma unroll
    for(int j=0;j<64;j++) y[j] += h*w2[j];
  }

  // residual + LayerNorm fully in-lane
  float mu=0.f;
  #pragma unroll
  for(int j=0;j<64;j++){ y[j] += x[j]; mu += y[j]; }
  mu *= (1.f/64.f);
  float var=0.f;
  #pragma unroll
  for(int j=0;j<64;j++){ float d=y[j]-mu; var += d*d; }
  float sc = rsqrtf(var*(1.f/64.f) + 1e-5f);
  #pragma unroll
  for(int i=0;i<16;i++){
    float4 o;
    o.x=(y[4*i  ]-mu)*sc*g2[4*i  ]+be2[4*i  ];
    o.y=(y[4*i+1]-mu)*sc*g2[4*i+1]+be2[4*i+1];
    o.z=(y[4*i+2]-mu)*sc*g2[4*i+2]+be2[4*i+2];
    o.w=(y[4*i+3]-mu)*sc*g2[4*i+3]+be2[4*i+3];
    ((float4*)base)[i]=o;
  }
}

// ---------------- prediction head ----------------
__global__ void k_head(const float* __restrict__ seq, const float* __restrict__ Wh,
                       const float* __restrict__ bh, float* __restrict__ out){
  int m = blockIdx.x*256 + threadIdx.x; if(m>=M_) return;
  const float* row = seq + ((size_t)11*M_ + m)*64;
  float a0=bh[0], a1=bh[1], a2=bh[2];
  #pragma unroll
  for(int d=0;d<64;d++){
    float x = row[d];
    a0 += x*Wh[d]; a1 += x*Wh[64+d]; a2 += x*Wh[128+d];
  }
  unsigned b=(unsigned)m/N_, n=(unsigned)m-b*N_;
  out[(b*3+0)*N_+n] = a0;
  out[(b*3+1)*N_+n] = a1;
  out[(b*3+2)*N_+n] = a2;
}

extern "C" void kernel_launch(void* const* d_in, const int* in_sizes, int n_in,
                              void* d_out, int out_size, void* d_ws, size_t ws_size,
                              hipStream_t stream)
{
  const float* x_seq=(const float*)d_in[0];
  const int*   ei   =(const int*)d_in[1];
  const float* W1   =(const float*)d_in[2];
  const float* as1  =(const float*)d_in[3];
  const float* ad1  =(const float*)d_in[4];
  const float* b1   =(const float*)d_in[5];
  const float* W2   =(const float*)d_in[6];
  const float* as2  =(const float*)d_in[7];
  const float* ad2  =(const float*)d_in[8];
  const float* b2   =(const float*)d_in[9];
  const float* Wqkv =(const float*)d_in[10];
  const float* bqkv =(const float*)d_in[11];
  const float* Wo   =(const float*)d_in[12];
  const float* bo   =(const float*)d_in[13];
  const float* Wf1  =(const float*)d_in[14];
  const float* bf1p =(const float*)d_in[15];
  const float* Wf2  =(const float*)d_in[16];
  const float* bf2p =(const float*)d_in[17];
  const float* g1   =(const float*)d_in[18];
  const float* be1  =(const float*)d_in[19];
  const float* g2   =(const float*)d_in[20];
  const float* be2  =(const float*)d_in[21];
  const float* Wh   =(const float*)d_in[22];
  const float* bh   =(const float*)d_in[23];

  // workspace layout (~120 MB)
  float* seq  = (float*)d_ws;            // [T][M][64]    24,576,000 f
  float* asc  = seq  + 24576000;         // [TB_][M][4]      512,000 f
  float* adc  = asc  + 512000;           //                  512,000 f
  float* W2T  = adc  + 512000;           // [2][128][64]      16,384 f
  int* deg    = (int*)(W2T + 16384);
  int* cursor = deg + M_;
  int* offs   = cursor + M_;             // M_+1 used
  int* bsums  = offs + (M_ + 2);
  int* boffs  = bsums + 128;
  int* csr    = boffs + 128;             // ETOT
  u16* h2u    = (u16*)(csr + ETOT);      // [TB_][M][64]  8,192,000 u16
  u16* wqP    = h2u + (size_t)TB_*M_*64; // 24576
  u16* woP    = wqP + 24576;             // 8192

  k_prep   <<<dim3(192), dim3(256), 0, stream>>>(Wqkv, Wo, Wf2, wqP, woP, W2T);

  // CSR build (edge list identical for all t)
  k_zero   <<<dim3((2*M_+255)/256), dim3(256), 0, stream>>>(deg, 2*M_);
  k_hist   <<<dim3((ETOT+255)/256), dim3(256), 0, stream>>>(ei, deg);
  k_scan1  <<<dim3(125), dim3(256), 0, stream>>>(deg, offs, bsums);
  k_scan2  <<<dim3(1),   dim3(128), 0, stream>>>(bsums, boffs);
  k_scan3  <<<dim3(125), dim3(256), 0, stream>>>(offs, boffs);
  k_scatter<<<dim3((ETOT+255)/256), dim3(256), 0, stream>>>(ei, offs, cursor, csr);

  for(int t0=0; t0<T_; t0+=TB_){
    k_gat12<<<dim3(500,TB_), dim3(256), 0, stream>>>(x_seq, W1, as1, ad1, b1,
                                                     W2, as2, ad2, offs, csr, h2u, asc, adc, t0);
    k_gat2b<<<dim3(500,TB_), dim3(256), 0, stream>>>(h2u, asc, adc, b2, offs, csr, seq, t0);
  }

  for(int i=0;i<2;i++){
    k_attn<<<dim3(8000), dim3(256), 0, stream>>>(seq,
        wqP + (size_t)i*12288, woP + (size_t)i*4096,
        bqkv + (size_t)i*192,  bo   + (size_t)i*64,
        g1   + (size_t)i*64,   be1  + (size_t)i*64);
    k_ff  <<<dim3(1500), dim3(256), 0, stream>>>(seq,
        Wf1  + (size_t)i*8192, bf1p + (size_t)i*128,
        W2T  + (size_t)i*8192, bf2p + (size_t)i*64,
        g2   + (size_t)i*64,   be2  + (size_t)i*64);
  }

  k_head<<<dim3(125), dim3(256), 0, stream>>>(seq, Wh, bh, (float*)d_out);
}